// Round 11
// baseline (400.536 us; speedup 1.0000x reference)
//
#include <hip/hip_runtime.h>
#include <hip/hip_bf16.h>
#include <cstdint>
#include <math.h>

#define D_DIM 1024
#define TAU_INV 10.0f
// K stored as e4m3(64 * k_hat): acc = 4096 * sim -> exp(acc * TAU_INV/4096)
#define EXP_SCALE (TAU_INV / 4096.0f)
#define BK 64                  // 64 fp8 = 64 B per row chunk (same as R10's 32 bf16)
#define NT (D_DIM / BK)        // 16 K-tiles
#define BM 256                 // A-tile rows
#define BN 128                 // B-tile rows (cols of S)
#define SLOT 24576             // ring slot: A 16K + B 8K

typedef int   i32x4  __attribute__((ext_vector_type(4)));
typedef int   i32x8  __attribute__((ext_vector_type(8)));
typedef float f32x16 __attribute__((ext_vector_type(16)));

#define VMCNT(n) asm volatile("s_waitcnt vmcnt(" #n ")" ::: "memory")
#define LGKM0()  asm volatile("s_waitcnt lgkmcnt(0)" ::: "memory")
#define BAR() do { asm volatile("" ::: "memory"); \
                   __builtin_amdgcn_s_barrier();  \
                   asm volatile("" ::: "memory"); } while (0)

__device__ __forceinline__ float wave_reduce_add(float v) {
#pragma unroll
    for (int off = 32; off > 0; off >>= 1) v += __shfl_xor(v, off, 64);
    return v;
}

// ---- Kernel A (fused): normalize -> fp8 K (x64 pre-scale), positives, zero rowsum
__global__ __launch_bounds__(256)
void norm_pos_kernel(const float* __restrict__ zi, const float* __restrict__ zj,
                     unsigned int* __restrict__ Kf, float* __restrict__ rowsum,
                     float* __restrict__ pos, int n_half) {
    const int i = blockIdx.x;
    const int t = threadIdx.x;                 // 256 threads x 4 floats = 1024
    float4 a = reinterpret_cast<const float4*>(zi + (size_t)i * D_DIM)[t];
    float4 b = reinterpret_cast<const float4*>(zj + (size_t)i * D_DIM)[t];
    float ssa = a.x*a.x + a.y*a.y + a.z*a.z + a.w*a.w;
    float ssb = b.x*b.x + b.y*b.y + b.z*b.z + b.w*b.w;
    float dab = a.x*b.x + a.y*b.y + a.z*b.z + a.w*b.w;
    ssa = wave_reduce_add(ssa);
    ssb = wave_reduce_add(ssb);
    dab = wave_reduce_add(dab);
    __shared__ float wsa[4], wsb[4], wsd[4];
    if ((t & 63) == 0) { wsa[t>>6] = ssa; wsb[t>>6] = ssb; wsd[t>>6] = dab; }
    __syncthreads();
    const float inva = 1.0f / sqrtf(wsa[0] + wsa[1] + wsa[2] + wsa[3]);
    const float invb = 1.0f / sqrtf(wsb[0] + wsb[1] + wsb[2] + wsb[3]);
    const float sa = inva * 64.0f;             // x64: keeps e4m3 in normal range
    const float sb = invb * 64.0f;
    unsigned int ua = 0, ub = 0;
    ua = __builtin_amdgcn_cvt_pk_fp8_f32(a.x * sa, a.y * sa, ua, false);
    ua = __builtin_amdgcn_cvt_pk_fp8_f32(a.z * sa, a.w * sa, ua, true);
    ub = __builtin_amdgcn_cvt_pk_fp8_f32(b.x * sb, b.y * sb, ub, false);
    ub = __builtin_amdgcn_cvt_pk_fp8_f32(b.z * sb, b.w * sb, ub, true);
    Kf[(size_t)i * 256 + t] = ua;                          // 1024 B row = 256 u32
    Kf[(size_t)(i + n_half) * 256 + t] = ub;
    if (t == 0) {
        pos[i] = (wsd[0] + wsd[1] + wsd[2] + wsd[3]) * inva * invb;
        rowsum[i] = 0.0f;
        rowsum[i + n_half] = 0.0f;
    }
}

// ---- Kernel B: triangular 256x128 tiles of S, fp8 MX MFMA, R10 schedule ----
// R10 pipe audit: LDS-read 47% busy was the rising bottleneck; fp8 halves
// LDS bytes, staging bytes, HBM fetch AND uses the 2x-rate MX pipe
// (mfma_scale_f32_32x32x64_f8f6f4, unit E8M0 scales = 0x7F).
// Structure identical to R10 (verified race-free, 0-conflict): 8 waves of
// 64x64 (now 2x2 of 32x32 frags), BK=64B rows, ring-3 LDS 72 KiB ->
// 2 blocks/CU, 1 barrier per K-tile, counted VMCNT(3), dist-2 prefetch,
// swizzle phys_slot = slot ^ ((row>>1)&3) inverse-applied at the source.
// Per K-tile t (slot s=t%3):
//   readA(2 frags, 4 b128) + readB(2 frags, 4 b128)
//   stage_all(t+2)  [3 gloads/thread]
//   mma mi=0 (2 MFMA)            [B/A1 read latency hides here]
//   LGKM0 ; VMCNT(3) ; BAR       [drain own reads; publish tile t+1]
//   mma mi=1 (2 MFMA)            [regs only]
// C/D 32x32 layout: col = lane&31, row = (reg&3) + 8*(reg>>2) + 4*(lane>>5).
__global__ __launch_bounds__(512, 4)
void simclr_gemm_kernel(const unsigned char* __restrict__ Kmat,
                        float* __restrict__ rowsum, int n_total) {
    __shared__ char lds[73728];

    const int tid  = threadIdx.x;
    const int lane = tid & 63;
    const int wave = tid >> 6;          // 0..7
    const int wr = wave >> 1;           // 0..3  (A rows wr*64)
    const int wc = wave & 1;            // 0..1  (B cols wc*64)
    const int kh = lane >> 5;           // 32B k-half within 64B row

    // bijective XCD swizzle: nwg = 1056 = 8 * 132
    const int wg = (blockIdx.x & 7) * 132 + (blockIdx.x >> 3);

    // decode wg -> (by, bx): by in [0,32), bx in [2*by, 64)
    int by = 0, start = 0;
    while (wg >= start + (64 - 2 * by)) { start += 64 - 2 * by; ++by; }
    const int bx = 2 * by + (wg - start);
    const bool diag = ((bx >> 1) == by);
    const int rowbase = by * BM;
    const int colbase = bx * BN;

    const char* gK = reinterpret_cast<const char*>(Kmat);
    const int srow = tid >> 2;                          // 0..127 per 8KB issue
    const int sswz = (tid & 3) ^ ((srow >> 1) & 3);     // inverse-swizzled slot

    // stage full K-tile tt into ring slot tt%3: A 2 issues + B 1 issue
    auto stage_all = [&](int tt) {
        const int s = tt % 3;
        const size_t kbyte = (size_t)tt * BK;           // 64 B per row chunk
        char* dstA = lds + s * SLOT + tid * 16;
        char* dstB = lds + s * SLOT + 16384 + tid * 16;
#pragma unroll
        for (int i = 0; i < 2; ++i) {
            const int row = i * 128 + srow;
            const char* src = gK + (size_t)(rowbase + row) * D_DIM + kbyte + sswz * 16;
            __builtin_amdgcn_global_load_lds(
                (const __attribute__((address_space(1))) void*)src,
                (__attribute__((address_space(3))) void*)(dstA + i * 8192),
                16, 0, 0);
        }
        {
            const char* src = gK + (size_t)(colbase + srow) * D_DIM + kbyte + sswz * 16;
            __builtin_amdgcn_global_load_lds(
                (const __attribute__((address_space(1))) void*)src,
                (__attribute__((address_space(3))) void*)dstB,
                16, 0, 0);
        }
    };

    f32x16 acc[2][2] = {};     // [mi][ni], 32x32 frags
    i32x8 af[2], bf[2];

    auto read_frag = [&](const char* base, int row) -> i32x8 {
        const int x = (row >> 1) & 3;
        const int s0 = kh * 2;
        i32x4 lo = *reinterpret_cast<const i32x4*>(base + row * 64 + ((s0 ^ x) << 4));
        i32x4 hi = *reinterpret_cast<const i32x4*>(base + row * 64 + (((s0 + 1) ^ x) << 4));
        return __builtin_shufflevector(lo, hi, 0, 1, 2, 3, 4, 5, 6, 7);
    };
    auto readA = [&](int s) {
        const char* Ab = lds + s * SLOT;
#pragma unroll
        for (int mi = 0; mi < 2; ++mi)
            af[mi] = read_frag(Ab, wr * 64 + mi * 32 + (lane & 31));
    };
    auto readB = [&](int s) {
        const char* Bb = lds + s * SLOT + 16384;
#pragma unroll
        for (int ni = 0; ni < 2; ++ni)
            bf[ni] = read_frag(Bb, wc * 64 + ni * 32 + (lane & 31));
    };
    auto mma_row = [&](int mi) {
        __builtin_amdgcn_s_setprio(1);
#pragma unroll
        for (int ni = 0; ni < 2; ++ni)
            acc[mi][ni] = __builtin_amdgcn_mfma_scale_f32_32x32x64_f8f6f4(
                af[mi], bf[ni], acc[mi][ni],
                0, 0,                       // cbsz=FP8, blgp=FP8
                0, 0x7f7f7f7f,              // scale A = 1.0 (E8M0 127)
                0, 0x7f7f7f7f);             // scale B = 1.0
        __builtin_amdgcn_s_setprio(0);
    };

    // prologue: tiles 0,1 staged; publish tile 0 (leave tile 1's 3 in flight)
    stage_all(0); stage_all(1);
    VMCNT(3); BAR();

    for (int t = 0; t < NT; ++t) {
        const int s = t % 3;
        readA(s); readB(s);                             // 8 ds_reads up-front
        if (t + 2 < NT) stage_all(t + 2);               // early prefetch issue
        mma_row(0);                                     // read latency hides
        if (t < NT - 1) {
            LGKM0();                                    // drain own reads pre-BAR
            if (t < NT - 2) { VMCNT(3); } else { VMCNT(0); }
            BAR();                                      // publish tile t+1
        }
        mma_row(1);                                     // regs only; overlaps
    }                                                   // next read issue

    // Epilogue. 32x32 C-frag: col = lane&31, row = (reg&3)+8*(reg>>2)+4*(lane>>5).
    float colpart[2] = {0.0f, 0.0f};
#pragma unroll
    for (int mi = 0; mi < 2; ++mi) {
#pragma unroll
        for (int reg = 0; reg < 16; ++reg) {
            const int grow = rowbase + wr * 64 + mi * 32 +
                             (reg & 3) + 8 * (reg >> 2) + 4 * (lane >> 5);
            float rowpart = 0.0f;
#pragma unroll
            for (int ni = 0; ni < 2; ++ni) {
                const int gcol = colbase + wc * 64 + ni * 32 + (lane & 31);
                float e = __expf(acc[mi][ni][reg] * EXP_SCALE);
                if (diag && grow == gcol) e = 0.0f;
                rowpart += e;
                colpart[ni] += e;
            }
#pragma unroll
            for (int off = 1; off < 32; off <<= 1)      // reduce over lane&31
                rowpart += __shfl_xor(rowpart, off, 64);
            if ((lane & 31) == 0) atomicAdd(&rowsum[grow], rowpart);
        }
    }
    if (!diag) {
#pragma unroll
        for (int ni = 0; ni < 2; ++ni) {
            float cp = colpart[ni];
            cp += __shfl_xor(cp, 32, 64);               // merge lane-halves
            if (lane < 32)
                atomicAdd(&rowsum[colbase + wc * 64 + ni * 32 + lane], cp);
        }
    }
}

// ---- Kernel C: loss = mean(log(denom) - pos/tau) ---------------------------
__global__ __launch_bounds__(256)
void loss_kernel(const float* __restrict__ rowsum, const float* __restrict__ pos,
                 float* __restrict__ out, int n_total, int n_half) {
    const int t = threadIdx.x;
    float acc = 0.0f;
    for (int r = t; r < n_total; r += 256) {
        const int pi = (r < n_half) ? r : (r - n_half);
        acc += logf(rowsum[r]) - TAU_INV * pos[pi];
    }
    acc = wave_reduce_add(acc);
    __shared__ float ws4[4];
    if ((t & 63) == 0) ws4[t >> 6] = acc;
    __syncthreads();
    if (t == 0) out[0] = (ws4[0] + ws4[1] + ws4[2] + ws4[3]) / (float)n_total;
}

extern "C" void kernel_launch(void* const* d_in, const int* in_sizes, int n_in,
                              void* d_out, int out_size, void* d_ws, size_t ws_size,
                              hipStream_t stream) {
    const float* zi = (const float*)d_in[0];
    const float* zj = (const float*)d_in[1];
    float* out = (float*)d_out;

    const int n_half  = in_sizes[0] / D_DIM;   // 4096
    const int n_total = 2 * n_half;            // 8192

    char* ws = (char*)d_ws;
    unsigned int* Kf = (unsigned int*)ws;                 // 8192 x 1024 fp8 = 8 MB
    size_t off = (size_t)n_total * D_DIM;
    float* rowsum = (float*)(ws + off); off += (size_t)n_total * 4;
    float* pos    = (float*)(ws + off); off += (size_t)n_half * 4;

    norm_pos_kernel<<<n_half, 256, 0, stream>>>(zi, zj, Kf, rowsum, pos, n_half);

    // triangular 256x128 tiles: sum_{by=0}^{31} (64 - 2*by) = 1056 blocks
    simclr_gemm_kernel<<<1056, 512, 0, stream>>>((const unsigned char*)Kf,
                                                 rowsum, n_total);

    loss_kernel<<<1, 256, 0, stream>>>(rowsum, pos, out, n_total, n_half);
}

// Round 12
// 390.459 us; speedup vs baseline: 1.0258x; 1.0258x over previous
//
#include <hip/hip_runtime.h>
#include <hip/hip_bf16.h>
#include <cstdint>
#include <math.h>

#define D_DIM 1024
#define TAU_INV 10.0f
// K stored as e4m3(64 * k_hat): acc = 4096 * sim -> exp(acc * TAU_INV/4096)
#define EXP_SCALE (TAU_INV / 4096.0f)
#define BK 64                  // 64 fp8 = 64 B per row chunk
#define NT (D_DIM / BK)        // 16 K-tiles
#define BM 256                 // A-tile rows
#define BN 128                 // B-tile rows (cols of S)
#define SLOT 24576             // ring slot: A 16K + B 8K

typedef int   i32x4  __attribute__((ext_vector_type(4)));
typedef int   i32x8  __attribute__((ext_vector_type(8)));
typedef float f32x16 __attribute__((ext_vector_type(16)));

#define VMCNT(n) asm volatile("s_waitcnt vmcnt(" #n ")" ::: "memory")
#define LGKM0()  asm volatile("s_waitcnt lgkmcnt(0)" ::: "memory")
#define BAR() do { asm volatile("" ::: "memory"); \
                   __builtin_amdgcn_s_barrier();  \
                   asm volatile("" ::: "memory"); } while (0)

__device__ __forceinline__ float wave_reduce_add(float v) {
#pragma unroll
    for (int off = 32; off > 0; off >>= 1) v += __shfl_xor(v, off, 64);
    return v;
}

// ---- Kernel A (fused): normalize -> fp8 K (x64 pre-scale), positives, zero rowsum
__global__ __launch_bounds__(256)
void norm_pos_kernel(const float* __restrict__ zi, const float* __restrict__ zj,
                     unsigned int* __restrict__ Kf, float* __restrict__ rowsum,
                     float* __restrict__ pos, int n_half) {
    const int i = blockIdx.x;
    const int t = threadIdx.x;                 // 256 threads x 4 floats = 1024
    float4 a = reinterpret_cast<const float4*>(zi + (size_t)i * D_DIM)[t];
    float4 b = reinterpret_cast<const float4*>(zj + (size_t)i * D_DIM)[t];
    float ssa = a.x*a.x + a.y*a.y + a.z*a.z + a.w*a.w;
    float ssb = b.x*b.x + b.y*b.y + b.z*b.z + b.w*b.w;
    float dab = a.x*b.x + a.y*b.y + a.z*b.z + a.w*b.w;
    ssa = wave_reduce_add(ssa);
    ssb = wave_reduce_add(ssb);
    dab = wave_reduce_add(dab);
    __shared__ float wsa[4], wsb[4], wsd[4];
    if ((t & 63) == 0) { wsa[t>>6] = ssa; wsb[t>>6] = ssb; wsd[t>>6] = dab; }
    __syncthreads();
    const float inva = 1.0f / sqrtf(wsa[0] + wsa[1] + wsa[2] + wsa[3]);
    const float invb = 1.0f / sqrtf(wsb[0] + wsb[1] + wsb[2] + wsb[3]);
    const float sa = inva * 64.0f;             // x64: keeps e4m3 in normal range
    const float sb = invb * 64.0f;
    unsigned int ua = 0, ub = 0;
    ua = __builtin_amdgcn_cvt_pk_fp8_f32(a.x * sa, a.y * sa, ua, false);
    ua = __builtin_amdgcn_cvt_pk_fp8_f32(a.z * sa, a.w * sa, ua, true);
    ub = __builtin_amdgcn_cvt_pk_fp8_f32(b.x * sb, b.y * sb, ub, false);
    ub = __builtin_amdgcn_cvt_pk_fp8_f32(b.z * sb, b.w * sb, ub, true);
    Kf[(size_t)i * 256 + t] = ua;                          // 1024 B row = 256 u32
    Kf[(size_t)(i + n_half) * 256 + t] = ub;
    if (t == 0) {
        pos[i] = (wsd[0] + wsd[1] + wsd[2] + wsd[3]) * inva * invb;
        rowsum[i] = 0.0f;
        rowsum[i + n_half] = 0.0f;
    }
}

// ---- Kernel B: triangular 256x128 tiles of S, fp8 MX MFMA, R10 schedule ----
// R11's failure was rule #20: f32x16 acc[2][2] behind a lambda went to scratch
// (WRITE_SIZE 737 MB). V12: NAMED accumulators acc00..acc11 and named operand
// frags af0/af1/bf0/bf1 -- zero arrays of wide vectors, all indices static.
// Schedule/geometry identical to R10/R11 (race-free since R4): 8 waves of
// 64x64 (2x2 of 32x32 MX frags), BK=64B rows, ring-3 LDS 72 KiB ->
// 2 blocks/CU, 1 barrier per K-tile, counted VMCNT(3), dist-2 prefetch,
// swizzle phys_slot = slot ^ ((row>>1)&3) inverse-applied at the source.
// C/D 32x32 layout: col = lane&31, row = (reg&3) + 8*(reg>>2) + 4*(lane>>5).
__global__ __launch_bounds__(512, 4)
void simclr_gemm_kernel(const unsigned char* __restrict__ Kmat,
                        float* __restrict__ rowsum, int n_total) {
    __shared__ char lds[73728];

    const int tid  = threadIdx.x;
    const int lane = tid & 63;
    const int wave = tid >> 6;          // 0..7
    const int wr = wave >> 1;           // 0..3  (A rows wr*64)
    const int wc = wave & 1;            // 0..1  (B cols wc*64)
    const int kh = lane >> 5;           // 32B k-half within 64B row

    // bijective XCD swizzle: nwg = 1056 = 8 * 132
    const int wg = (blockIdx.x & 7) * 132 + (blockIdx.x >> 3);

    // decode wg -> (by, bx): by in [0,32), bx in [2*by, 64)
    int by = 0, start = 0;
    while (wg >= start + (64 - 2 * by)) { start += 64 - 2 * by; ++by; }
    const int bx = 2 * by + (wg - start);
    const bool diag = ((bx >> 1) == by);
    const int rowbase = by * BM;
    const int colbase = bx * BN;

    const char* gK = reinterpret_cast<const char*>(Kmat);
    const int srow = tid >> 2;                          // 0..127 per 8KB issue
    const int sswz = (tid & 3) ^ ((srow >> 1) & 3);     // inverse-swizzled slot

    // stage full K-tile tt into ring slot tt%3: A 2 issues + B 1 issue
    auto stage_all = [&](int tt) {
        const int s = tt % 3;
        const size_t kbyte = (size_t)tt * BK;           // 64 B per row chunk
        char* dstA = lds + s * SLOT + tid * 16;
        char* dstB = lds + s * SLOT + 16384 + tid * 16;
#pragma unroll
        for (int i = 0; i < 2; ++i) {
            const int row = i * 128 + srow;
            const char* src = gK + (size_t)(rowbase + row) * D_DIM + kbyte + sswz * 16;
            __builtin_amdgcn_global_load_lds(
                (const __attribute__((address_space(1))) void*)src,
                (__attribute__((address_space(3))) void*)(dstA + i * 8192),
                16, 0, 0);
        }
        {
            const char* src = gK + (size_t)(colbase + srow) * D_DIM + kbyte + sswz * 16;
            __builtin_amdgcn_global_load_lds(
                (const __attribute__((address_space(1))) void*)src,
                (__attribute__((address_space(3))) void*)dstB,
                16, 0, 0);
        }
    };

    // NAMED wide-vector registers (rule #20: no arrays of f32x16/i32x8)
    f32x16 acc00 = {}, acc01 = {}, acc10 = {}, acc11 = {};
    i32x8 af0, af1, bf0, bf1;

    auto read_frag = [&](const char* base, int row) -> i32x8 {
        const int x = (row >> 1) & 3;
        const int s0 = kh * 2;
        i32x4 lo = *reinterpret_cast<const i32x4*>(base + row * 64 + ((s0 ^ x) << 4));
        i32x4 hi = *reinterpret_cast<const i32x4*>(base + row * 64 + (((s0 + 1) ^ x) << 4));
        return __builtin_shufflevector(lo, hi, 0, 1, 2, 3, 4, 5, 6, 7);
    };

    // prologue: tiles 0,1 staged; publish tile 0 (leave tile 1's 3 in flight)
    stage_all(0); stage_all(1);
    VMCNT(3); BAR();

    for (int t = 0; t < NT; ++t) {
        const int s = t % 3;
        const char* Ab = lds + s * SLOT;
        const char* Bb = lds + s * SLOT + 16384;
        af0 = read_frag(Ab, wr * 64 +  0 + (lane & 31));
        af1 = read_frag(Ab, wr * 64 + 32 + (lane & 31));
        bf0 = read_frag(Bb, wc * 64 +  0 + (lane & 31));
        bf1 = read_frag(Bb, wc * 64 + 32 + (lane & 31));
        if (t + 2 < NT) stage_all(t + 2);               // early prefetch issue
        __builtin_amdgcn_s_setprio(1);
        acc00 = __builtin_amdgcn_mfma_scale_f32_32x32x64_f8f6f4(
            af0, bf0, acc00, 0, 0, 0, 0x7f7f7f7f, 0, 0x7f7f7f7f);
        acc01 = __builtin_amdgcn_mfma_scale_f32_32x32x64_f8f6f4(
            af0, bf1, acc01, 0, 0, 0, 0x7f7f7f7f, 0, 0x7f7f7f7f);
        __builtin_amdgcn_s_setprio(0);
        if (t < NT - 1) {
            LGKM0();                                    // drain own reads pre-BAR
            if (t < NT - 2) { VMCNT(3); } else { VMCNT(0); }
            BAR();                                      // publish tile t+1
        }
        __builtin_amdgcn_s_setprio(1);
        acc10 = __builtin_amdgcn_mfma_scale_f32_32x32x64_f8f6f4(
            af1, bf0, acc10, 0, 0, 0, 0x7f7f7f7f, 0, 0x7f7f7f7f);
        acc11 = __builtin_amdgcn_mfma_scale_f32_32x32x64_f8f6f4(
            af1, bf1, acc11, 0, 0, 0, 0x7f7f7f7f, 0, 0x7f7f7f7f);
        __builtin_amdgcn_s_setprio(0);
    }

    // Epilogue. 32x32 C-frag: col = lane&31, row = (reg&3)+8*(reg>>2)+4*(lane>>5).
    float cp0 = 0.0f, cp1 = 0.0f;    // column partials for ni=0 / ni=1
    const int gcol0 = colbase + wc * 64 +  0 + (lane & 31);
    const int gcol1 = colbase + wc * 64 + 32 + (lane & 31);

    auto epi_pair = [&](const f32x16& a0, const f32x16& a1, int mi) {
#pragma unroll
        for (int reg = 0; reg < 16; ++reg) {
            const int grow = rowbase + wr * 64 + mi * 32 +
                             (reg & 3) + 8 * (reg >> 2) + 4 * (lane >> 5);
            float e0 = __expf(a0[reg] * EXP_SCALE);
            float e1 = __expf(a1[reg] * EXP_SCALE);
            if (diag && grow == gcol0) e0 = 0.0f;
            if (diag && grow == gcol1) e1 = 0.0f;
            float rowpart = e0 + e1;
            cp0 += e0; cp1 += e1;
#pragma unroll
            for (int off = 1; off < 32; off <<= 1)      // reduce over lane&31
                rowpart += __shfl_xor(rowpart, off, 64);
            if ((lane & 31) == 0) atomicAdd(&rowsum[grow], rowpart);
        }
    };
    epi_pair(acc00, acc01, 0);
    epi_pair(acc10, acc11, 1);

    if (!diag) {
        cp0 += __shfl_xor(cp0, 32, 64);                 // merge lane-halves
        cp1 += __shfl_xor(cp1, 32, 64);
        if (lane < 32) {
            atomicAdd(&rowsum[colbase + wc * 64 +  0 + lane], cp0);
            atomicAdd(&rowsum[colbase + wc * 64 + 32 + lane], cp1);
        }
    }
}

// ---- Kernel C: loss = mean(log(denom) - pos/tau) ---------------------------
__global__ __launch_bounds__(256)
void loss_kernel(const float* __restrict__ rowsum, const float* __restrict__ pos,
                 float* __restrict__ out, int n_total, int n_half) {
    const int t = threadIdx.x;
    float acc = 0.0f;
    for (int r = t; r < n_total; r += 256) {
        const int pi = (r < n_half) ? r : (r - n_half);
        acc += logf(rowsum[r]) - TAU_INV * pos[pi];
    }
    acc = wave_reduce_add(acc);
    __shared__ float ws4[4];
    if ((t & 63) == 0) ws4[t >> 6] = acc;
    __syncthreads();
    if (t == 0) out[0] = (ws4[0] + ws4[1] + ws4[2] + ws4[3]) / (float)n_total;
}

extern "C" void kernel_launch(void* const* d_in, const int* in_sizes, int n_in,
                              void* d_out, int out_size, void* d_ws, size_t ws_size,
                              hipStream_t stream) {
    const float* zi = (const float*)d_in[0];
    const float* zj = (const float*)d_in[1];
    float* out = (float*)d_out;

    const int n_half  = in_sizes[0] / D_DIM;   // 4096
    const int n_total = 2 * n_half;            // 8192

    char* ws = (char*)d_ws;
    unsigned int* Kf = (unsigned int*)ws;                 // 8192 x 1024 fp8 = 8 MB
    size_t off = (size_t)n_total * D_DIM;
    float* rowsum = (float*)(ws + off); off += (size_t)n_total * 4;
    float* pos    = (float*)(ws + off); off += (size_t)n_half * 4;

    norm_pos_kernel<<<n_half, 256, 0, stream>>>(zi, zj, Kf, rowsum, pos, n_half);

    // triangular 256x128 tiles: sum_{by=0}^{31} (64 - 2*by) = 1056 blocks
    simclr_gemm_kernel<<<1056, 512, 0, stream>>>((const unsigned char*)Kf,
                                                 rowsum, n_total);

    loss_kernel<<<1, 256, 0, stream>>>(rowsum, pos, out, n_total, n_half);
}

// Round 13
// 88.527 us; speedup vs baseline: 4.5244x; 4.4106x over previous
//
#include <hip/hip_runtime.h>
#include <hip/hip_bf16.h>
#include <cstdint>
#include <math.h>

#define D_DIM 1024
#define TAU_INV 10.0f
// K stored as e4m3(64 * k_hat): acc = 4096 * sim -> exp(acc * TAU_INV/4096)
#define EXP_SCALE (TAU_INV / 4096.0f)
#define BK 64                  // 64 fp8 = 64 B per row chunk
#define NT (D_DIM / BK)        // 16 K-tiles
#define BM 256                 // A-tile rows
#define BN 128                 // B-tile rows (cols of S)
#define SLOT 24576             // ring slot: A 16K + B 8K

typedef float f32x4 __attribute__((ext_vector_type(4)));

#define VMCNT(n) asm volatile("s_waitcnt vmcnt(" #n ")" ::: "memory")
#define LGKM0()  asm volatile("s_waitcnt lgkmcnt(0)" ::: "memory")
#define BAR() do { asm volatile("" ::: "memory"); \
                   __builtin_amdgcn_s_barrier();  \
                   asm volatile("" ::: "memory"); } while (0)

__device__ __forceinline__ float wave_reduce_add(float v) {
#pragma unroll
    for (int off = 32; off > 0; off >>= 1) v += __shfl_xor(v, off, 64);
    return v;
}

// ---- Kernel A (fused): normalize -> fp8 K (x64 pre-scale), positives, zero rowsum
__global__ __launch_bounds__(256)
void norm_pos_kernel(const float* __restrict__ zi, const float* __restrict__ zj,
                     unsigned int* __restrict__ Kf, float* __restrict__ rowsum,
                     float* __restrict__ pos, int n_half) {
    const int i = blockIdx.x;
    const int t = threadIdx.x;                 // 256 threads x 4 floats = 1024
    float4 a = reinterpret_cast<const float4*>(zi + (size_t)i * D_DIM)[t];
    float4 b = reinterpret_cast<const float4*>(zj + (size_t)i * D_DIM)[t];
    float ssa = a.x*a.x + a.y*a.y + a.z*a.z + a.w*a.w;
    float ssb = b.x*b.x + b.y*b.y + b.z*b.z + b.w*b.w;
    float dab = a.x*b.x + a.y*b.y + a.z*b.z + a.w*b.w;
    ssa = wave_reduce_add(ssa);
    ssb = wave_reduce_add(ssb);
    dab = wave_reduce_add(dab);
    __shared__ float wsa[4], wsb[4], wsd[4];
    if ((t & 63) == 0) { wsa[t>>6] = ssa; wsb[t>>6] = ssb; wsd[t>>6] = dab; }
    __syncthreads();
    const float inva = 1.0f / sqrtf(wsa[0] + wsa[1] + wsa[2] + wsa[3]);
    const float invb = 1.0f / sqrtf(wsb[0] + wsb[1] + wsb[2] + wsb[3]);
    const float sa = inva * 64.0f;             // x64: keeps e4m3 in normal range
    const float sb = invb * 64.0f;
    unsigned int ua = 0, ub = 0;
    ua = __builtin_amdgcn_cvt_pk_fp8_f32(a.x * sa, a.y * sa, ua, false);
    ua = __builtin_amdgcn_cvt_pk_fp8_f32(a.z * sa, a.w * sa, ua, true);
    ub = __builtin_amdgcn_cvt_pk_fp8_f32(b.x * sb, b.y * sb, ub, false);
    ub = __builtin_amdgcn_cvt_pk_fp8_f32(b.z * sb, b.w * sb, ub, true);
    Kf[(size_t)i * 256 + t] = ua;                          // 1024 B row = 256 u32
    Kf[(size_t)(i + n_half) * 256 + t] = ub;
    if (t == 0) {
        pos[i] = (wsd[0] + wsd[1] + wsd[2] + wsd[3]) * inva * invb;
        rowsum[i] = 0.0f;
        rowsum[i + n_half] = 0.0f;
    }
}

// ---- Kernel B: triangular 256x128 tiles of S, fp8 plain MFMA, R10 schedule -
// R12 falsified rule-#20 fix -> spill is specific to mfma_scale (acc stays in
// arch VGPRs). This round: PLAIN mfma_f32_16x16x32_fp8_fp8 -- identical
// f32x4/AGPR accumulator structure to the proven R10 bf16 kernel, operands
// are 8-byte (long) frags. fp8 halves LDS bytes, staging bytes, FETCH and
// barrier count (NT 32->16); MFMA rate = bf16 rate (unchanged).
//
// Geometry/schedule = R10 exactly (race-free since R4, 0-conflict swizzle):
// 8 waves of 64x64 (4x4 of 16x16 frags), 64B LDS rows, ring-3 LDS 72 KiB ->
// 2 blocks/CU, 1 barrier per K-tile, counted VMCNT(3), dist-2 prefetch,
// 16B-slot swizzle phys = slot ^ ((row>>1)&3), inverse-applied at source.
// Fragment read: k-half h of kgrp g = 8B at logical byte h*32 + g*8 ->
// ds_read_b64 at phys slot ((h*2 + (g>>1)) ^ xr)*16 + (g&1)*8. Bank check:
// 16 lanes -> banks 16*(row&1) + 4*(slot^xr) + 2*(g&1) -> 8 distinct, 2
// lanes/bank = conflict-free (m136: 2-way free).
// Per K-tile: 16 ds_read_b64 (halves-first issue) + 32 MFMA split 16+16
// around {LGKM0; VMCNT; BAR} exactly as R10.
__global__ __launch_bounds__(512, 4)
void simclr_gemm_kernel(const unsigned char* __restrict__ Kmat,
                        float* __restrict__ rowsum, int n_total) {
    __shared__ char lds[73728];

    const int tid  = threadIdx.x;
    const int lane = tid & 63;
    const int wave = tid >> 6;          // 0..7
    const int wr = wave >> 1;           // 0..3  (A rows wr*64)
    const int wc = wave & 1;            // 0..1  (B cols wc*64)
    const int kgrp = lane >> 4;         // 8B k-slot within a 32B k-half

    // bijective XCD swizzle: nwg = 1056 = 8 * 132
    const int wg = (blockIdx.x & 7) * 132 + (blockIdx.x >> 3);

    // decode wg -> (by, bx): by in [0,32), bx in [2*by, 64)
    int by = 0, start = 0;
    while (wg >= start + (64 - 2 * by)) { start += 64 - 2 * by; ++by; }
    const int bx = 2 * by + (wg - start);
    const bool diag = ((bx >> 1) == by);
    const int rowbase = by * BM;
    const int colbase = bx * BN;

    const char* gK = reinterpret_cast<const char*>(Kmat);
    const int srow = tid >> 2;                          // 0..127 per 8KB issue
    const int sswz = (tid & 3) ^ ((srow >> 1) & 3);     // inverse-swizzled slot

    // stage full K-tile tt into ring slot tt%3: A 2 issues + B 1 issue
    auto stage_all = [&](int tt) {
        const int s = tt % 3;
        const size_t kbyte = (size_t)tt * BK;           // 64 B per row chunk
        char* dstA = lds + s * SLOT + tid * 16;
        char* dstB = lds + s * SLOT + 16384 + tid * 16;
#pragma unroll
        for (int i = 0; i < 2; ++i) {
            const int row = i * 128 + srow;
            const char* src = gK + (size_t)(rowbase + row) * D_DIM + kbyte + sswz * 16;
            __builtin_amdgcn_global_load_lds(
                (const __attribute__((address_space(1))) void*)src,
                (__attribute__((address_space(3))) void*)(dstA + i * 8192),
                16, 0, 0);
        }
        {
            const char* src = gK + (size_t)(colbase + srow) * D_DIM + kbyte + sswz * 16;
            __builtin_amdgcn_global_load_lds(
                (const __attribute__((address_space(1))) void*)src,
                (__attribute__((address_space(3))) void*)dstB,
                16, 0, 0);
        }
    };

    f32x4 acc[4][4] = {};              // [mi][ni] 16x16 frags (AGPR path)
    long af0[4], af1[4], bf0[4], bf1[4];   // 8B fp8 frags, k-half 0/1

    // k-half h fragment of row: logical bytes h*32 + kgrp*8 .. +8
    auto read_half = [&](const char* base, int row, int h) -> long {
        const int xr = (row >> 1) & 3;
        const int s  = h * 2 + (kgrp >> 1);             // 16B slot 0..3
        return *reinterpret_cast<const long*>(
            base + row * 64 + ((s ^ xr) << 4) + (kgrp & 1) * 8);
    };

    // prologue: tiles 0,1 staged; publish tile 0 (leave tile 1's 3 in flight)
    stage_all(0); stage_all(1);
    VMCNT(3); BAR();

    for (int t = 0; t < NT; ++t) {
        const int s = t % 3;
        const char* Ab = lds + s * SLOT;
        const char* Bb = Ab + 16384;
        // issue k-half-0 reads first (8 b64), then k-half-1 (8 b64):
        // compiler's counted lgkm lets mma half-0 start after the first 8.
#pragma unroll
        for (int mi = 0; mi < 4; ++mi)
            af0[mi] = read_half(Ab, wr * 64 + mi * 16 + (lane & 15), 0);
#pragma unroll
        for (int ni = 0; ni < 4; ++ni)
            bf0[ni] = read_half(Bb, wc * 64 + ni * 16 + (lane & 15), 0);
#pragma unroll
        for (int mi = 0; mi < 4; ++mi)
            af1[mi] = read_half(Ab, wr * 64 + mi * 16 + (lane & 15), 1);
#pragma unroll
        for (int ni = 0; ni < 4; ++ni)
            bf1[ni] = read_half(Bb, wc * 64 + ni * 16 + (lane & 15), 1);
        if (t + 2 < NT) stage_all(t + 2);               // early prefetch issue
        __builtin_amdgcn_s_setprio(1);
#pragma unroll
        for (int mi = 0; mi < 4; ++mi)
#pragma unroll
            for (int ni = 0; ni < 4; ++ni)
                acc[mi][ni] = __builtin_amdgcn_mfma_f32_16x16x32_fp8_fp8(
                    af0[mi], bf0[ni], acc[mi][ni], 0, 0, 0);
        __builtin_amdgcn_s_setprio(0);
        if (t < NT - 1) {
            LGKM0();                                    // drain own reads pre-BAR
            if (t < NT - 2) { VMCNT(3); } else { VMCNT(0); }
            BAR();                                      // publish tile t+1
        }
        __builtin_amdgcn_s_setprio(1);
#pragma unroll
        for (int mi = 0; mi < 4; ++mi)
#pragma unroll
            for (int ni = 0; ni < 4; ++ni)
                acc[mi][ni] = __builtin_amdgcn_mfma_f32_16x16x32_fp8_fp8(
                    af1[mi], bf1[ni], acc[mi][ni], 0, 0, 0);
        __builtin_amdgcn_s_setprio(0);
    }

    // Epilogue. C-frag: col = lane&15, row = (lane>>4)*4 + reg.
    float colpart[4] = {0.0f, 0.0f, 0.0f, 0.0f};
#pragma unroll
    for (int mi = 0; mi < 4; ++mi) {
#pragma unroll
        for (int reg = 0; reg < 4; ++reg) {
            const int grow = rowbase + wr * 64 + mi * 16 + ((lane >> 4) << 2) + reg;
            float rowpart = 0.0f;
#pragma unroll
            for (int ni = 0; ni < 4; ++ni) {
                const int gcol = colbase + wc * 64 + ni * 16 + (lane & 15);
                float e = __expf(acc[mi][ni][reg] * EXP_SCALE);
                if (diag && grow == gcol) e = 0.0f;
                rowpart += e;
                colpart[ni] += e;
            }
#pragma unroll
            for (int off = 1; off < 16; off <<= 1)
                rowpart += __shfl_xor(rowpart, off, 64);
            if ((lane & 15) == 0) atomicAdd(&rowsum[grow], rowpart);
        }
    }
    if (!diag) {
#pragma unroll
        for (int ni = 0; ni < 4; ++ni) {
            float cp = colpart[ni];
            cp += __shfl_xor(cp, 16, 64);
            cp += __shfl_xor(cp, 32, 64);
            if (lane < 16)
                atomicAdd(&rowsum[colbase + wc * 64 + ni * 16 + lane], cp);
        }
    }
}

// ---- Kernel C: loss = mean(log(denom) - pos/tau) ---------------------------
__global__ __launch_bounds__(256)
void loss_kernel(const float* __restrict__ rowsum, const float* __restrict__ pos,
                 float* __restrict__ out, int n_total, int n_half) {
    const int t = threadIdx.x;
    float acc = 0.0f;
    for (int r = t; r < n_total; r += 256) {
        const int pi = (r < n_half) ? r : (r - n_half);
        acc += logf(rowsum[r]) - TAU_INV * pos[pi];
    }
    acc = wave_reduce_add(acc);
    __shared__ float ws4[4];
    if ((t & 63) == 0) ws4[t >> 6] = acc;
    __syncthreads();
    if (t == 0) out[0] = (ws4[0] + ws4[1] + ws4[2] + ws4[3]) / (float)n_total;
}

extern "C" void kernel_launch(void* const* d_in, const int* in_sizes, int n_in,
                              void* d_out, int out_size, void* d_ws, size_t ws_size,
                              hipStream_t stream) {
    const float* zi = (const float*)d_in[0];
    const float* zj = (const float*)d_in[1];
    float* out = (float*)d_out;

    const int n_half  = in_sizes[0] / D_DIM;   // 4096
    const int n_total = 2 * n_half;            // 8192

    char* ws = (char*)d_ws;
    unsigned int* Kf = (unsigned int*)ws;                 // 8192 x 1024 fp8 = 8 MB
    size_t off = (size_t)n_total * D_DIM;
    float* rowsum = (float*)(ws + off); off += (size_t)n_total * 4;
    float* pos    = (float*)(ws + off); off += (size_t)n_half * 4;

    norm_pos_kernel<<<n_half, 256, 0, stream>>>(zi, zj, Kf, rowsum, pos, n_half);

    // triangular 256x128 tiles: sum_{by=0}^{31} (64 - 2*by) = 1056 blocks
    simclr_gemm_kernel<<<1056, 512, 0, stream>>>((const unsigned char*)Kf,
                                                 rowsum, n_total);

    loss_kernel<<<1, 256, 0, stream>>>(rowsum, pos, out, n_total, n_half);
}

// Round 14
// 82.206 us; speedup vs baseline: 4.8724x; 1.0769x over previous
//
#include <hip/hip_runtime.h>
#include <hip/hip_bf16.h>
#include <cstdint>
#include <math.h>

#define D_DIM 1024
#define TAU_INV 10.0f
// K stored as e4m3(64 * k_hat): acc = 4096 * sim -> exp(acc * TAU_INV/4096)
#define EXP_SCALE (TAU_INV / 4096.0f)
#define BK 64                  // 64 fp8 = 64 B per row chunk
#define NT (D_DIM / BK)        // 16 K-tiles
#define BM 256                 // A-tile rows
#define BN 128                 // B-tile rows (cols of S)
#define SLOT 24576             // ring slot: A 16K + B 8K

typedef float f32x4 __attribute__((ext_vector_type(4)));
typedef long  l64x2 __attribute__((ext_vector_type(2)));

#define VMCNT(n) asm volatile("s_waitcnt vmcnt(" #n ")" ::: "memory")
#define LGKM0()  asm volatile("s_waitcnt lgkmcnt(0)" ::: "memory")
#define BAR() do { asm volatile("" ::: "memory"); \
                   __builtin_amdgcn_s_barrier();  \
                   asm volatile("" ::: "memory"); } while (0)

__device__ __forceinline__ float wave_reduce_add(float v) {
#pragma unroll
    for (int off = 32; off > 0; off >>= 1) v += __shfl_xor(v, off, 64);
    return v;
}

// ---- Kernel A (fused): normalize -> fp8 K (x64 pre-scale, INTERLEAVED),
//      positives, zero rowsum.
// Interleaved row layout: within each 64B K-tile chunk, 8B chunks are ordered
// [g0h0][g0h1][g1h0][g1h1][g2h0][g2h1][g3h0][g3h1] (g = kgrp, h = K=32 half),
// so a GEMM lane's full fragment (both halves) is one contiguous 16B slot.
// Thread t produces logical k = 4t..4t+3 -> physical word
// w = (t>>4)*16 + ((t>>1)&3)*4 + ((t>>3)&1)*2 + (t&1)  (bijective).
__global__ __launch_bounds__(256)
void norm_pos_kernel(const float* __restrict__ zi, const float* __restrict__ zj,
                     unsigned int* __restrict__ Kf, float* __restrict__ rowsum,
                     float* __restrict__ pos, int n_half) {
    const int i = blockIdx.x;
    const int t = threadIdx.x;                 // 256 threads x 4 floats = 1024
    float4 a = reinterpret_cast<const float4*>(zi + (size_t)i * D_DIM)[t];
    float4 b = reinterpret_cast<const float4*>(zj + (size_t)i * D_DIM)[t];
    float ssa = a.x*a.x + a.y*a.y + a.z*a.z + a.w*a.w;
    float ssb = b.x*b.x + b.y*b.y + b.z*b.z + b.w*b.w;
    float dab = a.x*b.x + a.y*b.y + a.z*b.z + a.w*b.w;
    ssa = wave_reduce_add(ssa);
    ssb = wave_reduce_add(ssb);
    dab = wave_reduce_add(dab);
    __shared__ float wsa[4], wsb[4], wsd[4];
    if ((t & 63) == 0) { wsa[t>>6] = ssa; wsb[t>>6] = ssb; wsd[t>>6] = dab; }
    __syncthreads();
    const float inva = 1.0f / sqrtf(wsa[0] + wsa[1] + wsa[2] + wsa[3]);
    const float invb = 1.0f / sqrtf(wsb[0] + wsb[1] + wsb[2] + wsb[3]);
    const float sa = inva * 64.0f;             // x64: keeps e4m3 in normal range
    const float sb = invb * 64.0f;
    unsigned int ua = 0, ub = 0;
    ua = __builtin_amdgcn_cvt_pk_fp8_f32(a.x * sa, a.y * sa, ua, false);
    ua = __builtin_amdgcn_cvt_pk_fp8_f32(a.z * sa, a.w * sa, ua, true);
    ub = __builtin_amdgcn_cvt_pk_fp8_f32(b.x * sb, b.y * sb, ub, false);
    ub = __builtin_amdgcn_cvt_pk_fp8_f32(b.z * sb, b.w * sb, ub, true);
    const int w = (t >> 4) * 16 + ((t >> 1) & 3) * 4 + ((t >> 3) & 1) * 2 + (t & 1);
    Kf[(size_t)i * 256 + w] = ua;                          // 1024 B row = 256 u32
    Kf[(size_t)(i + n_half) * 256 + w] = ub;
    if (t == 0) {
        pos[i] = (wsd[0] + wsd[1] + wsd[2] + wsd[3]) * inva * invb;
        rowsum[i] = 0.0f;
        rowsum[i + n_half] = 0.0f;
    }
}

// ---- Kernel B: triangular 256x128 tiles of S, fp8 plain MFMA ----------------
// R13 lesson: fp8 b64 fragment reads were a structural 2-way phase conflict
// (8.65M conflict cycles). With the interleaved global layout, each fragment
// is ONE ds_read_b128 at R7's measured-0-conflict address pattern:
//   row*64 + ((kgrp ^ ((row>>1)&3)) << 4)
// 8 b128 per K-tile per wave (was 16 b64). Everything else identical to
// R13/R10 (race-free since R4): 8 waves of 64x64, 64B LDS rows, ring-3 LDS
// 72 KiB -> 2 blocks/CU, 1 barrier/K-tile, counted VMCNT(3), dist-2 prefetch,
// 16B-slot swizzle phys = slot ^ ((row>>1)&3) inverse-applied at the source.
// Per K-tile: 8 b128 reads up-front, 16 MFMA (k-half lo), {LGKM0;VMCNT;BAR},
// 16 MFMA (k-half hi, regs only).
__global__ __launch_bounds__(512, 4)
void simclr_gemm_kernel(const unsigned char* __restrict__ Kmat,
                        float* __restrict__ rowsum, int n_total) {
    __shared__ char lds[73728];

    const int tid  = threadIdx.x;
    const int lane = tid & 63;
    const int wave = tid >> 6;          // 0..7
    const int wr = wave >> 1;           // 0..3  (A rows wr*64)
    const int wc = wave & 1;            // 0..1  (B cols wc*64)
    const int kgrp = lane >> 4;         // 16B fragment slot within 64B row

    // bijective XCD swizzle: nwg = 1056 = 8 * 132
    const int wg = (blockIdx.x & 7) * 132 + (blockIdx.x >> 3);

    // decode wg -> (by, bx): by in [0,32), bx in [2*by, 64)
    int by = 0, start = 0;
    while (wg >= start + (64 - 2 * by)) { start += 64 - 2 * by; ++by; }
    const int bx = 2 * by + (wg - start);
    const bool diag = ((bx >> 1) == by);
    const int rowbase = by * BM;
    const int colbase = bx * BN;

    const char* gK = reinterpret_cast<const char*>(Kmat);
    const int srow = tid >> 2;                          // 0..127 per 8KB issue
    const int sswz = (tid & 3) ^ ((srow >> 1) & 3);     // inverse-swizzled slot

    // stage full K-tile tt into ring slot tt%3: A 2 issues + B 1 issue
    auto stage_all = [&](int tt) {
        const int s = tt % 3;
        const size_t kbyte = (size_t)tt * BK;           // 64 B per row chunk
        char* dstA = lds + s * SLOT + tid * 16;
        char* dstB = lds + s * SLOT + 16384 + tid * 16;
#pragma unroll
        for (int i = 0; i < 2; ++i) {
            const int row = i * 128 + srow;
            const char* src = gK + (size_t)(rowbase + row) * D_DIM + kbyte + sswz * 16;
            __builtin_amdgcn_global_load_lds(
                (const __attribute__((address_space(1))) void*)src,
                (__attribute__((address_space(3))) void*)(dstA + i * 8192),
                16, 0, 0);
        }
        {
            const char* src = gK + (size_t)(colbase + srow) * D_DIM + kbyte + sswz * 16;
            __builtin_amdgcn_global_load_lds(
                (const __attribute__((address_space(1))) void*)src,
                (__attribute__((address_space(3))) void*)dstB,
                16, 0, 0);
        }
    };

    f32x4 acc[4][4] = {};              // [mi][ni] 16x16 frags (AGPR path)
    l64x2 af[4], bf[4];                // 16B fragments: .x = k-half0, .y = k-half1

    auto read_frag = [&](const char* base, int row) -> l64x2 {
        return *reinterpret_cast<const l64x2*>(
            base + row * 64 + ((kgrp ^ ((row >> 1) & 3)) << 4));
    };

    // prologue: tiles 0,1 staged; publish tile 0 (leave tile 1's 3 in flight)
    stage_all(0); stage_all(1);
    VMCNT(3); BAR();

    for (int t = 0; t < NT; ++t) {
        const int s = t % 3;
        const char* Ab = lds + s * SLOT;
        const char* Bb = Ab + 16384;
#pragma unroll
        for (int mi = 0; mi < 4; ++mi)
            af[mi] = read_frag(Ab, wr * 64 + mi * 16 + (lane & 15));
#pragma unroll
        for (int ni = 0; ni < 4; ++ni)
            bf[ni] = read_frag(Bb, wc * 64 + ni * 16 + (lane & 15));
        if (t + 2 < NT) stage_all(t + 2);               // early prefetch issue
        __builtin_amdgcn_s_setprio(1);
#pragma unroll
        for (int mi = 0; mi < 4; ++mi)
#pragma unroll
            for (int ni = 0; ni < 4; ++ni)
                acc[mi][ni] = __builtin_amdgcn_mfma_f32_16x16x32_fp8_fp8(
                    af[mi].x, bf[ni].x, acc[mi][ni], 0, 0, 0);
        __builtin_amdgcn_s_setprio(0);
        if (t < NT - 1) {
            LGKM0();                                    // drain own reads pre-BAR
            if (t < NT - 2) { VMCNT(3); } else { VMCNT(0); }
            BAR();                                      // publish tile t+1
        }
        __builtin_amdgcn_s_setprio(1);
#pragma unroll
        for (int mi = 0; mi < 4; ++mi)
#pragma unroll
            for (int ni = 0; ni < 4; ++ni)
                acc[mi][ni] = __builtin_amdgcn_mfma_f32_16x16x32_fp8_fp8(
                    af[mi].y, bf[ni].y, acc[mi][ni], 0, 0, 0);
        __builtin_amdgcn_s_setprio(0);
    }

    // Epilogue. C-frag: col = lane&15, row = (lane>>4)*4 + reg.
    float colpart[4] = {0.0f, 0.0f, 0.0f, 0.0f};
#pragma unroll
    for (int mi = 0; mi < 4; ++mi) {
#pragma unroll
        for (int reg = 0; reg < 4; ++reg) {
            const int grow = rowbase + wr * 64 + mi * 16 + ((lane >> 4) << 2) + reg;
            float rowpart = 0.0f;
#pragma unroll
            for (int ni = 0; ni < 4; ++ni) {
                const int gcol = colbase + wc * 64 + ni * 16 + (lane & 15);
                float e = __expf(acc[mi][ni][reg] * EXP_SCALE);
                if (diag && grow == gcol) e = 0.0f;
                rowpart += e;
                colpart[ni] += e;
            }
#pragma unroll
            for (int off = 1; off < 16; off <<= 1)
                rowpart += __shfl_xor(rowpart, off, 64);
            if ((lane & 15) == 0) atomicAdd(&rowsum[grow], rowpart);
        }
    }
    if (!diag) {
#pragma unroll
        for (int ni = 0; ni < 4; ++ni) {
            float cp = colpart[ni];
            cp += __shfl_xor(cp, 16, 64);
            cp += __shfl_xor(cp, 32, 64);
            if (lane < 16)
                atomicAdd(&rowsum[colbase + wc * 64 + ni * 16 + lane], cp);
        }
    }
}

// ---- Kernel C: loss = mean(log(denom) - pos/tau) ---------------------------
__global__ __launch_bounds__(256)
void loss_kernel(const float* __restrict__ rowsum, const float* __restrict__ pos,
                 float* __restrict__ out, int n_total, int n_half) {
    const int t = threadIdx.x;
    float acc = 0.0f;
    for (int r = t; r < n_total; r += 256) {
        const int pi = (r < n_half) ? r : (r - n_half);
        acc += logf(rowsum[r]) - TAU_INV * pos[pi];
    }
    acc = wave_reduce_add(acc);
    __shared__ float ws4[4];
    if ((t & 63) == 0) ws4[t >> 6] = acc;
    __syncthreads();
    if (t == 0) out[0] = (ws4[0] + ws4[1] + ws4[2] + ws4[3]) / (float)n_total;
}

extern "C" void kernel_launch(void* const* d_in, const int* in_sizes, int n_in,
                              void* d_out, int out_size, void* d_ws, size_t ws_size,
                              hipStream_t stream) {
    const float* zi = (const float*)d_in[0];
    const float* zj = (const float*)d_in[1];
    float* out = (float*)d_out;

    const int n_half  = in_sizes[0] / D_DIM;   // 4096
    const int n_total = 2 * n_half;            // 8192

    char* ws = (char*)d_ws;
    unsigned int* Kf = (unsigned int*)ws;                 // 8192 x 1024 fp8 = 8 MB
    size_t off = (size_t)n_total * D_DIM;
    float* rowsum = (float*)(ws + off); off += (size_t)n_total * 4;
    float* pos    = (float*)(ws + off); off += (size_t)n_half * 4;

    norm_pos_kernel<<<n_half, 256, 0, stream>>>(zi, zj, Kf, rowsum, pos, n_half);

    // triangular 256x128 tiles: sum_{by=0}^{31} (64 - 2*by) = 1056 blocks
    simclr_gemm_kernel<<<1056, 512, 0, stream>>>((const unsigned char*)Kf,
                                                 rowsum, n_total);

    loss_kernel<<<1, 256, 0, stream>>>(rowsum, pos, out, n_total, n_half);
}